// Round 3
// baseline (114.424 us; speedup 1.0000x reference)
//
#include <hip/hip_runtime.h>

typedef float f4 __attribute__((ext_vector_type(4)));

// Problem constants (from reference)
#define BB 256      // batch (both expert and violator)
#define SS 2048     // sequence
#define DD 128      // feature dim
#define MARGIN 10.0f
#define ALPHA 3.0f
#define BETA 0.3f
#define GAMMA 0.3f

// ws layout (floats):
//   [0      .. 65535]  centroids: 512 rows x 128 (expert 0..255, violator 256..511)
//   [65536  .. 66047]  norms: 512 (||centroid||^2)
//   [66048  .. 66303]  sep partials: 256
//   [66304]            done-counter (unsigned int), reset by centroid_kernel
#define WS_CENT   0
#define WS_NORMS  65536
#define WS_PART   66048
#define WS_CNT    66304

// Kernel 1: per (tensor,batch) centroid + squared norm.
// grid = 512, block = 1024 (16 waves). tid = ssub*32 + d4.
// A wave's load covers 1 KB contiguous. 4 independent accumulators for MLP;
// nontemporal loads (data is read exactly once).
__global__ __launch_bounds__(1024) void centroid_kernel(
    const float* __restrict__ E, const float* __restrict__ V,
    float* __restrict__ cent, float* __restrict__ norms,
    unsigned int* __restrict__ counter)
{
    const int p = blockIdx.x;
    const float* src = (p < BB) ? (E + (size_t)p * SS * DD)
                                : (V + (size_t)(p - BB) * SS * DD);
    const f4* src4 = reinterpret_cast<const f4*>(src);

    const int tid  = threadIdx.x;
    const int d4   = tid & 31;   // float4 column 0..31
    const int ssub = tid >> 5;   // row slice 0..31

    // reset the fused-kernel's done counter for this launch (kernel-boundary
    // ordering guarantees visibility before sep_finalize_kernel starts)
    if (p == 0 && tid == 0) *counter = 0u;

    const f4* p4 = src4 + (size_t)ssub * 32 + d4;
    f4 a0 = 0.f, a1 = 0.f, a2 = 0.f, a3 = 0.f;
    #pragma unroll 2
    for (int it = 0; it < 16; ++it) {
        f4 x0 = __builtin_nontemporal_load(p4);
        f4 x1 = __builtin_nontemporal_load(p4 + 1024);
        f4 x2 = __builtin_nontemporal_load(p4 + 2048);
        f4 x3 = __builtin_nontemporal_load(p4 + 3072);
        a0 += x0; a1 += x1; a2 += x2; a3 += x3;
        p4 += 4096;
    }
    f4 acc = (a0 + a1) + (a2 + a3);

    // lanes l and l+32 hold adjacent row-slices at the same d4 -> combine
    acc.x += __shfl_down(acc.x, 32);
    acc.y += __shfl_down(acc.y, 32);
    acc.z += __shfl_down(acc.z, 32);
    acc.w += __shfl_down(acc.w, 32);

    __shared__ f4 red[512];      // 16 waves x 32 columns
    if ((tid & 63) < 32) red[(tid >> 6) * 32 + (tid & 63)] = acc;
    __syncthreads();
    for (int h = 8; h >= 1; h >>= 1) {
        if (tid < h * 32) red[tid] += red[tid + h * 32];
        __syncthreads();
    }

    if (tid < 32) {
        f4 c = red[tid] * (1.0f / (float)SS);
        reinterpret_cast<f4*>(cent)[p * 32 + tid] = c;
        float n = c.x * c.x + c.y * c.y + c.z * c.z + c.w * c.w;
        // threads 0..31 are lanes 0..31 of wave 0; tree feeds only from <32
        n += __shfl_down(n, 16);
        n += __shfl_down(n, 8);
        n += __shfl_down(n, 4);
        n += __shfl_down(n, 2);
        n += __shfl_down(n, 1);
        if (tid == 0) norms[p] = n;
    }
}

// Kernel 2 (fused): block i computes sep_i = sum_j clamp(M - dist(e_i,v_j),0)^2.
// Clustering losses use the closed form  sum_{i<j}||c_i-c_j||^2 = N*A - B
// with A = sum||c_i||^2, B = ||sum c_i||^2 (the max(.,0) clamp never binds:
// centroid sqdists ~0.125 >> 0). The last block to finish computes A, B,
// sums the sep partials in a fixed order, and writes the scalar loss.
__global__ __launch_bounds__(256) void sep_finalize_kernel(
    const float* __restrict__ cent, const float* __restrict__ norms,
    float* __restrict__ partials, unsigned int* __restrict__ counter,
    float* __restrict__ out)
{
    const int i = blockIdx.x;
    const int j = threadIdx.x;
    const f4* C4 = reinterpret_cast<const f4*>(cent);

    __shared__ f4 Ei[32];
    if (j < 32) Ei[j] = C4[i * 32 + j];
    __syncthreads();

    float dev = 0.f;
    #pragma unroll 8
    for (int q = 0; q < 32; ++q) {
        const f4 e  = Ei[q];
        const f4 vj = C4[(BB + j) * 32 + q];
        f4 t0 = e * vj;
        dev += t0.x + t0.y + t0.z + t0.w;
    }
    float sq_ev = fmaxf(norms[i] + norms[BB + j] - 2.0f * dev, 0.0f);
    float dist  = sqrtf(sq_ev + 1e-12f);
    float tt    = fmaxf(MARGIN - dist, 0.0f);
    float sep   = tt * tt;

    #pragma unroll
    for (int off = 32; off >= 1; off >>= 1) sep += __shfl_down(sep, off);
    __shared__ float wred[4];
    if ((j & 63) == 0) wred[j >> 6] = sep;
    __syncthreads();

    __shared__ unsigned int s_old;
    if (j == 0) {
        partials[i] = wred[0] + wred[1] + wred[2] + wred[3];
        __threadfence();                       // publish partial before ticket
        s_old = atomicAdd(counter, 1u);
    }
    __syncthreads();
    if (s_old != BB - 1) return;

    // ---- last block: finalize (values identical regardless of which block) ----
    __threadfence();                           // acquire side

    float a_e = norms[j];
    float a_v = norms[BB + j];
    float sp  = partials[j];

    // column sums for B terms: threads 0..127 -> expert dim d=j,
    // threads 128..255 -> violator dim d=j-128. Coalesced 512B per step, L2-hot.
    const float* base = (j < 128) ? cent : cent + BB * DD;
    const int d = j & 127;
    float cs = 0.f;
    #pragma unroll 4
    for (int ii = 0; ii < BB; ++ii) cs += base[ii * DD + d];
    float cs2 = cs * cs;

    __shared__ float sarr[256];
    sarr[j] = cs2;
    __syncthreads();
    for (int h = 64; h >= 1; h >>= 1) {
        if ((j & 127) < h) sarr[j] += sarr[j + h];
        __syncthreads();
    }
    // B_e = sarr[0], B_v = sarr[128]

    #pragma unroll
    for (int off = 32; off >= 1; off >>= 1) {
        a_e += __shfl_down(a_e, off);
        a_v += __shfl_down(a_v, off);
        sp  += __shfl_down(sp , off);
    }
    __shared__ float w3[4][3];
    if ((j & 63) == 0) {
        w3[j >> 6][0] = a_e;
        w3[j >> 6][1] = a_v;
        w3[j >> 6][2] = sp;
    }
    __syncthreads();

    if (j == 0) {
        float A_e = w3[0][0] + w3[1][0] + w3[2][0] + w3[3][0];
        float A_v = w3[0][1] + w3[1][1] + w3[2][1] + w3[3][1];
        float SP  = w3[0][2] + w3[1][2] + w3[2][2] + w3[3][2];
        float B_e = sarr[0];
        float B_v = sarr[128];

        const float cnt = (float)(BB * (BB - 1) / 2);   // 32640
        float ee_sum = fmaxf((float)BB * A_e - B_e, 0.0f);
        float vv_sum = fmaxf((float)BB * A_v - B_v, 0.0f);
        float sep_mean = SP / (float)(BB * BB);
        out[0] = ALPHA * sep_mean + (BETA * ee_sum + GAMMA * vv_sum) / cnt;
    }
}

extern "C" void kernel_launch(void* const* d_in, const int* in_sizes, int n_in,
                              void* d_out, int out_size, void* d_ws, size_t ws_size,
                              hipStream_t stream) {
    const float* E = (const float*)d_in[0];
    const float* V = (const float*)d_in[1];
    float* ws   = (float*)d_ws;
    float* cent = ws + WS_CENT;
    float* nrm  = ws + WS_NORMS;
    float* part = ws + WS_PART;
    unsigned int* cnt = (unsigned int*)(ws + WS_CNT);
    float* out  = (float*)d_out;

    centroid_kernel<<<512, 1024, 0, stream>>>(E, V, cent, nrm, cnt);
    sep_finalize_kernel<<<BB, 256, 0, stream>>>(cent, nrm, part, cnt, out);
}

// Round 4
// 109.599 us; speedup vs baseline: 1.0440x; 1.0440x over previous
//
#include <hip/hip_runtime.h>

typedef float f4 __attribute__((ext_vector_type(4)));

// Problem constants (from reference)
#define BB 256      // batch (both expert and violator)
#define SS 2048     // sequence
#define DD 128      // feature dim
#define MARGIN 10.0f
#define ALPHA 3.0f
#define BETA 0.3f
#define GAMMA 0.3f

// ws layout (floats):
//   [0      .. 65535]  centroids: 512 rows x 128 (expert 0..255, violator 256..511)
//   [65536  .. 66047]  norms: 512 (||centroid||^2)
//   [66048  .. 66303]  sep partials: 256
#define WS_CENT   0
#define WS_NORMS  65536
#define WS_PART   66048

// Kernel 1: per (tensor,batch) centroid + squared norm.
// grid = 512, block = 1024 (16 waves). tid = ssub*32 + d4.
// A wave's load covers 1 KB contiguous. 4 independent accumulators for MLP;
// nontemporal loads (data is read exactly once).
__global__ __launch_bounds__(1024) void centroid_kernel(
    const float* __restrict__ E, const float* __restrict__ V,
    float* __restrict__ cent, float* __restrict__ norms)
{
    const int p = blockIdx.x;
    const float* src = (p < BB) ? (E + (size_t)p * SS * DD)
                                : (V + (size_t)(p - BB) * SS * DD);
    const f4* src4 = reinterpret_cast<const f4*>(src);

    const int tid  = threadIdx.x;
    const int d4   = tid & 31;   // float4 column 0..31
    const int ssub = tid >> 5;   // row slice 0..31

    const f4* p4 = src4 + (size_t)ssub * 32 + d4;
    f4 a0 = 0.f, a1 = 0.f, a2 = 0.f, a3 = 0.f;
    #pragma unroll 2
    for (int it = 0; it < 16; ++it) {
        f4 x0 = __builtin_nontemporal_load(p4);
        f4 x1 = __builtin_nontemporal_load(p4 + 1024);
        f4 x2 = __builtin_nontemporal_load(p4 + 2048);
        f4 x3 = __builtin_nontemporal_load(p4 + 3072);
        a0 += x0; a1 += x1; a2 += x2; a3 += x3;
        p4 += 4096;
    }
    f4 acc = (a0 + a1) + (a2 + a3);

    // lanes l and l+32 hold adjacent row-slices at the same d4 -> combine
    acc.x += __shfl_down(acc.x, 32);
    acc.y += __shfl_down(acc.y, 32);
    acc.z += __shfl_down(acc.z, 32);
    acc.w += __shfl_down(acc.w, 32);

    __shared__ f4 red[512];      // 16 waves x 32 columns
    if ((tid & 63) < 32) red[(tid >> 6) * 32 + (tid & 63)] = acc;
    __syncthreads();
    for (int h = 8; h >= 1; h >>= 1) {
        if (tid < h * 32) red[tid] += red[tid + h * 32];
        __syncthreads();
    }

    if (tid < 32) {
        f4 c = red[tid] * (1.0f / (float)SS);
        reinterpret_cast<f4*>(cent)[p * 32 + tid] = c;
        float n = c.x * c.x + c.y * c.y + c.z * c.z + c.w * c.w;
        n += __shfl_down(n, 16);
        n += __shfl_down(n, 8);
        n += __shfl_down(n, 4);
        n += __shfl_down(n, 2);
        n += __shfl_down(n, 1);
        if (tid == 0) norms[p] = n;
    }
}

// Kernel 2: block i computes sep_i = sum_j clamp(MARGIN - dist(e_i, v_j), 0)^2.
// One dot-product per thread; violator centroids (128 KB) stay L2-resident.
__global__ __launch_bounds__(256) void sep_kernel(
    const float* __restrict__ cent, const float* __restrict__ norms,
    float* __restrict__ partials)
{
    const int i = blockIdx.x;
    const int j = threadIdx.x;
    const f4* C4 = reinterpret_cast<const f4*>(cent);

    __shared__ f4 Ei[32];
    if (j < 32) Ei[j] = C4[i * 32 + j];
    __syncthreads();

    float dev = 0.f;
    #pragma unroll 8
    for (int q = 0; q < 32; ++q) {
        const f4 e  = Ei[q];
        const f4 vj = C4[(BB + j) * 32 + q];
        f4 t0 = e * vj;
        dev += t0.x + t0.y + t0.z + t0.w;
    }
    float sq_ev = fmaxf(norms[i] + norms[BB + j] - 2.0f * dev, 0.0f);
    float dist  = sqrtf(sq_ev + 1e-12f);
    float tt    = fmaxf(MARGIN - dist, 0.0f);
    float sep   = tt * tt;

    #pragma unroll
    for (int off = 32; off >= 1; off >>= 1) sep += __shfl_down(sep, off);
    __shared__ float wred[4];
    if ((j & 63) == 0) wred[j >> 6] = sep;
    __syncthreads();
    if (j == 0) partials[i] = wred[0] + wred[1] + wred[2] + wred[3];
}

// Kernel 3: finalize. Clustering via closed form:
//   sum_{i<j}||c_i-c_j||^2 = N * sum_i||c_i||^2 - ||sum_i c_i||^2
// (the max(.,0) clamp never binds; validated absmax=0.0 in round 2).
__global__ __launch_bounds__(256) void finalize_kernel(
    const float* __restrict__ cent, const float* __restrict__ norms,
    const float* __restrict__ partials, float* __restrict__ out)
{
    const int j = threadIdx.x;

    float a_e = norms[j];
    float a_v = norms[BB + j];
    float sp  = partials[j];

    // column sums: threads 0..127 -> expert dim j, 128..255 -> violator dim j-128
    const float* base = (j < 128) ? cent : cent + BB * DD;
    const int d = j & 127;
    float cs = 0.f;
    #pragma unroll 4
    for (int ii = 0; ii < BB; ++ii) cs += base[ii * DD + d];
    float cs2 = cs * cs;

    __shared__ float sarr[256];
    sarr[j] = cs2;
    __syncthreads();
    for (int h = 64; h >= 1; h >>= 1) {
        if ((j & 127) < h) sarr[j] += sarr[j + h];
        __syncthreads();
    }
    // B_e = sarr[0], B_v = sarr[128]

    #pragma unroll
    for (int off = 32; off >= 1; off >>= 1) {
        a_e += __shfl_down(a_e, off);
        a_v += __shfl_down(a_v, off);
        sp  += __shfl_down(sp , off);
    }
    __shared__ float w3[4][3];
    if ((j & 63) == 0) {
        w3[j >> 6][0] = a_e;
        w3[j >> 6][1] = a_v;
        w3[j >> 6][2] = sp;
    }
    __syncthreads();

    if (j == 0) {
        float A_e = w3[0][0] + w3[1][0] + w3[2][0] + w3[3][0];
        float A_v = w3[0][1] + w3[1][1] + w3[2][1] + w3[3][1];
        float SP  = w3[0][2] + w3[1][2] + w3[2][2] + w3[3][2];
        float B_e = sarr[0];
        float B_v = sarr[128];

        const float cnt = (float)(BB * (BB - 1) / 2);   // 32640
        float ee_sum = fmaxf((float)BB * A_e - B_e, 0.0f);
        float vv_sum = fmaxf((float)BB * A_v - B_v, 0.0f);
        float sep_mean = SP / (float)(BB * BB);
        out[0] = ALPHA * sep_mean + (BETA * ee_sum + GAMMA * vv_sum) / cnt;
    }
}

extern "C" void kernel_launch(void* const* d_in, const int* in_sizes, int n_in,
                              void* d_out, int out_size, void* d_ws, size_t ws_size,
                              hipStream_t stream) {
    const float* E = (const float*)d_in[0];
    const float* V = (const float*)d_in[1];
    float* ws   = (float*)d_ws;
    float* cent = ws + WS_CENT;
    float* nrm  = ws + WS_NORMS;
    float* part = ws + WS_PART;
    float* out  = (float*)d_out;

    centroid_kernel<<<512, 1024, 0, stream>>>(E, V, cent, nrm);
    sep_kernel<<<BB, 256, 0, stream>>>(cent, nrm, part);
    finalize_kernel<<<1, 256, 0, stream>>>(cent, nrm, part, out);
}

// Round 5
// 97.406 us; speedup vs baseline: 1.1747x; 1.1252x over previous
//
#include <hip/hip_runtime.h>

typedef float f4 __attribute__((ext_vector_type(4)));

// Problem constants (from reference)
#define BB 256      // batch (both expert and violator)
#define SS 2048     // sequence
#define DD 128      // feature dim
#define MARGIN 10.0f
#define ALPHA 3.0f
#define BETA 0.3f
#define GAMMA 0.3f

// ws layout (floats):
//   [0      .. 65535]  centroids: 512 rows x 128 (expert 0..255, violator 256..511)
//   [65536  .. 66047]  norms: 512 (||centroid||^2)
//   [66048  .. 66303]  sep partials: 256
#define WS_CENT   0
#define WS_NORMS  65536
#define WS_PART   66048

// Kernel 1: per (tensor,batch) centroid + squared norm.
// grid = 512, block = 1024 (16 waves). tid = ssub*32 + d4.
// A wave's load covers 1 KB contiguous. 4 independent accumulators for MLP;
// nontemporal loads (data is read exactly once).
__global__ __launch_bounds__(1024) void centroid_kernel(
    const float* __restrict__ E, const float* __restrict__ V,
    float* __restrict__ cent, float* __restrict__ norms)
{
    const int p = blockIdx.x;
    const float* src = (p < BB) ? (E + (size_t)p * SS * DD)
                                : (V + (size_t)(p - BB) * SS * DD);
    const f4* src4 = reinterpret_cast<const f4*>(src);

    const int tid  = threadIdx.x;
    const int d4   = tid & 31;   // float4 column 0..31
    const int ssub = tid >> 5;   // row slice 0..31

    const f4* p4 = src4 + (size_t)ssub * 32 + d4;
    f4 a0 = 0.f, a1 = 0.f, a2 = 0.f, a3 = 0.f;
    #pragma unroll 2
    for (int it = 0; it < 16; ++it) {
        f4 x0 = __builtin_nontemporal_load(p4);
        f4 x1 = __builtin_nontemporal_load(p4 + 1024);
        f4 x2 = __builtin_nontemporal_load(p4 + 2048);
        f4 x3 = __builtin_nontemporal_load(p4 + 3072);
        a0 += x0; a1 += x1; a2 += x2; a3 += x3;
        p4 += 4096;
    }
    f4 acc = (a0 + a1) + (a2 + a3);

    // lanes l and l+32 hold adjacent row-slices at the same d4 -> combine
    acc.x += __shfl_down(acc.x, 32);
    acc.y += __shfl_down(acc.y, 32);
    acc.z += __shfl_down(acc.z, 32);
    acc.w += __shfl_down(acc.w, 32);

    __shared__ f4 red[512];      // 16 waves x 32 columns
    if ((tid & 63) < 32) red[(tid >> 6) * 32 + (tid & 63)] = acc;
    __syncthreads();
    for (int h = 8; h >= 1; h >>= 1) {
        if (tid < h * 32) red[tid] += red[tid + h * 32];
        __syncthreads();
    }

    if (tid < 32) {
        f4 c = red[tid] * (1.0f / (float)SS);
        reinterpret_cast<f4*>(cent)[p * 32 + tid] = c;
        float n = c.x * c.x + c.y * c.y + c.z * c.z + c.w * c.w;
        n += __shfl_down(n, 16);
        n += __shfl_down(n, 8);
        n += __shfl_down(n, 4);
        n += __shfl_down(n, 2);
        n += __shfl_down(n, 1);
        if (tid == 0) norms[p] = n;
    }
}

// Kernel 2: block i computes sep_i = sum_j clamp(MARGIN - dist(e_i, v_j), 0)^2.
// One dot-product per thread; violator centroids (128 KB) stay L2-resident.
__global__ __launch_bounds__(256) void sep_kernel(
    const float* __restrict__ cent, const float* __restrict__ norms,
    float* __restrict__ partials)
{
    const int i = blockIdx.x;
    const int j = threadIdx.x;
    const f4* C4 = reinterpret_cast<const f4*>(cent);

    __shared__ f4 Ei[32];
    if (j < 32) Ei[j] = C4[i * 32 + j];
    __syncthreads();

    float dev = 0.f;
    #pragma unroll 8
    for (int q = 0; q < 32; ++q) {
        const f4 e  = Ei[q];
        const f4 vj = C4[(BB + j) * 32 + q];
        f4 t0 = e * vj;
        dev += t0.x + t0.y + t0.z + t0.w;
    }
    float sq_ev = fmaxf(norms[i] + norms[BB + j] - 2.0f * dev, 0.0f);
    float dist  = sqrtf(sq_ev + 1e-12f);
    float tt    = fmaxf(MARGIN - dist, 0.0f);
    float sep   = tt * tt;

    #pragma unroll
    for (int off = 32; off >= 1; off >>= 1) sep += __shfl_down(sep, off);
    __shared__ float wred[4];
    if ((j & 63) == 0) wred[j >> 6] = sep;
    __syncthreads();
    if (j == 0) partials[i] = wred[0] + wred[1] + wred[2] + wred[3];
}

// Kernel 3: finalize (1024 threads, f4-vectorized, latency-parallel).
// Clustering via closed form: sum_{i<j}||c_i-c_j||^2 = N*A - B,
//   A = sum_i ||c_i||^2, B = ||sum_i c_i||^2  (clamp never binds; absmax=0.0
//   validated in rounds 2-4).
// Column sums: 64 chunks (half,d4), 16 threads/chunk, 16 independent f4 loads
// each (coalesced, all in flight -> ~one L3 latency, not 64 serialized).
__global__ __launch_bounds__(1024) void finalize_kernel(
    const float* __restrict__ cent, const float* __restrict__ norms,
    const float* __restrict__ partials, float* __restrict__ out)
{
    const int tid = threadIdx.x;
    const f4* C4 = reinterpret_cast<const f4*>(cent);

    const int chunk = tid & 63;      // (half<<5) | d4
    const int r     = tid >> 6;      // 0..15 row-slice
    const int half  = chunk >> 5;
    const int d4    = chunk & 31;
    const f4* basep = C4 + (size_t)(half * BB) * 32 + d4;

    f4 cs = 0.f;
    #pragma unroll
    for (int k = 0; k < 16; ++k)
        cs += basep[(size_t)(r + k * 16) * 32];

    __shared__ f4 red[1024];         // [r][chunk]
    red[tid] = cs;
    __syncthreads();
    #pragma unroll
    for (int h = 8; h >= 1; h >>= 1) {
        if (tid < h * 64) red[tid] += red[tid + h * 64];
        __syncthreads();
    }

    __shared__ float Bvals[2];
    if (tid < 64) {
        f4 c = red[tid];             // colsum f4 for chunk tid
        float b = c.x * c.x + c.y * c.y + c.z * c.z + c.w * c.w;
        #pragma unroll
        for (int off = 16; off >= 1; off >>= 1)
            b += __shfl_down(b, off, 32);     // reduce within 32-lane halves
        if ((tid & 31) == 0) Bvals[tid >> 5] = b;   // lanes 0,32 (wave 0)
    }

    // A_e, A_v, SP reductions (threads 0..255 contribute)
    float a_e = 0.f, a_v = 0.f, sp = 0.f;
    if (tid < BB) {
        a_e = norms[tid];
        a_v = norms[BB + tid];
        sp  = partials[tid];
    }
    #pragma unroll
    for (int off = 32; off >= 1; off >>= 1) {
        a_e += __shfl_down(a_e, off);
        a_v += __shfl_down(a_v, off);
        sp  += __shfl_down(sp , off);
    }
    __shared__ float w3[16][3];
    if ((tid & 63) == 0) {
        w3[tid >> 6][0] = a_e;
        w3[tid >> 6][1] = a_v;
        w3[tid >> 6][2] = sp;
    }
    __syncthreads();

    if (tid == 0) {
        float A_e = w3[0][0] + w3[1][0] + w3[2][0] + w3[3][0];
        float A_v = w3[0][1] + w3[1][1] + w3[2][1] + w3[3][1];
        float SP  = w3[0][2] + w3[1][2] + w3[2][2] + w3[3][2];
        float B_e = Bvals[0];
        float B_v = Bvals[1];

        const float cnt = (float)(BB * (BB - 1) / 2);   // 32640
        float ee_sum = fmaxf((float)BB * A_e - B_e, 0.0f);
        float vv_sum = fmaxf((float)BB * A_v - B_v, 0.0f);
        float sep_mean = SP / (float)(BB * BB);
        out[0] = ALPHA * sep_mean + (BETA * ee_sum + GAMMA * vv_sum) / cnt;
    }
}

extern "C" void kernel_launch(void* const* d_in, const int* in_sizes, int n_in,
                              void* d_out, int out_size, void* d_ws, size_t ws_size,
                              hipStream_t stream) {
    const float* E = (const float*)d_in[0];
    const float* V = (const float*)d_in[1];
    float* ws   = (float*)d_ws;
    float* cent = ws + WS_CENT;
    float* nrm  = ws + WS_NORMS;
    float* part = ws + WS_PART;
    float* out  = (float*)d_out;

    centroid_kernel<<<512, 1024, 0, stream>>>(E, V, cent, nrm);
    sep_kernel<<<BB, 256, 0, stream>>>(cent, nrm, part);
    finalize_kernel<<<1, 1024, 0, stream>>>(cent, nrm, part, out);
}